// Round 3
// baseline (1120.442 us; speedup 1.0000x reference)
//
#include <hip/hip_runtime.h>

// GCN forward on MI355X — bf16 intermediate pipeline.
// CSR build (bucket hist -> scan -> bucket scatter -> bucket_to_csr) ->
// gemm1 (MFMA bf16) -> spmm1(+b1,relu) -> gemm2 -> spmm2(+b2,log_softmax)
//
// CSR build rationale: direct per-row scatter has a 6.4 MB/XCD write frontier
// (100K rows x 64B lines) -> L2 thrash -> 8x write amplification (measured
// 198 MB for 25.6 MB payload, 260 us). Bucketing by row>>5 (3125 buckets)
// shrinks the frontier to ~400 KB/XCD -> ~1x amplification; per-bucket
// finalize scatters only within a 12 KB L2-resident window.

#define NN 100000
#define NE 3200000
#define FIN 512
#define FHID 128
#define FOUT 32
#define NBUCK 3125  // NN / 32 exactly

typedef __attribute__((ext_vector_type(8))) short bf16x8;
typedef __attribute__((ext_vector_type(4))) float f32x4;

static __device__ __forceinline__ unsigned short f2bf(float f) {
    unsigned u = __float_as_uint(f);
    unsigned r = (u + 0x7FFFu + ((u >> 16) & 1u)) >> 16;  // RTN-even
    return (unsigned short)r;
}
static __device__ __forceinline__ float bf2f(unsigned short u) {
    return __uint_as_float(((unsigned)u) << 16);
}

// ---------------- CSR build ----------------
__global__ __launch_bounds__(256) void bucket_hist(const int* __restrict__ erow,
                                                   int* __restrict__ bcnt) {
    int e = blockIdx.x * 256 + threadIdx.x;
    if (e < NE) atomicAdd(&bcnt[erow[e] >> 5], 1);
}

// single block, 1024 threads, scans 3125 bucket counts -> bstart (excl) + bfill copy
__global__ __launch_bounds__(1024) void bucket_scan(const int* __restrict__ bcnt,
                                                    int* __restrict__ bstart,
                                                    int* __restrict__ bfill) {
    __shared__ int s[1024];
    int t = threadIdx.x;
    int base = t * 4;
    int v[4];
#pragma unroll
    for (int j = 0; j < 4; ++j) v[j] = (base + j < NBUCK) ? bcnt[base + j] : 0;
    int lsum = v[0] + v[1] + v[2] + v[3];
    s[t] = lsum;
    __syncthreads();
    for (int o = 1; o < 1024; o <<= 1) {
        int xv = (t >= o) ? s[t - o] : 0;
        __syncthreads();
        s[t] += xv;
        __syncthreads();
    }
    int run = s[t] - lsum;
#pragma unroll
    for (int j = 0; j < 4; ++j) {
        if (base + j < NBUCK) {
            bstart[base + j] = run;
            bfill[base + j] = run;
        }
        run += v[j];
    }
    if (t == 1023) bstart[NBUCK] = s[1023];  // == NE
}

__global__ __launch_bounds__(256) void bucket_scatter(const int* __restrict__ erow,
                                                      const int* __restrict__ ecol,
                                                      const float* __restrict__ eval,
                                                      int* __restrict__ bfill,
                                                      int* __restrict__ brow,
                                                      int2* __restrict__ bcolval) {
    int e = blockIdx.x * 256 + threadIdx.x;
    if (e < NE) {
        int r = erow[e];
        int idx = atomicAdd(&bfill[r >> 5], 1);
        brow[idx] = r;
        bcolval[idx] = make_int2(ecol[e], __float_as_int(eval[e]));
    }
}

// one workgroup per bucket: count 32 rows, tiny scan, write rowptr, scatter
// bucket edges to final CSR position (writes confined to a ~12 KB window).
__global__ __launch_bounds__(256) void bucket_to_csr(const int* __restrict__ bstart,
                                                     const int* __restrict__ brow,
                                                     const int2* __restrict__ bcolval,
                                                     int* __restrict__ rowptr,
                                                     int2* __restrict__ epack) {
    __shared__ int cnt[32];
    __shared__ int pos[32];
    const int b = blockIdx.x;
    const int t = threadIdx.x;
    const int s0 = bstart[b];
    const int n = bstart[b + 1] - s0;
    if (t < 32) cnt[t] = 0;
    __syncthreads();
    for (int i = t; i < n; i += 256) atomicAdd(&cnt[brow[s0 + i] & 31], 1);
    __syncthreads();
    if (t == 0) {
        int run = 0;
#pragma unroll
        for (int i = 0; i < 32; ++i) {
            pos[i] = run;
            run += cnt[i];
        }
    }
    __syncthreads();
    if (t < 32) rowptr[b * 32 + t] = s0 + pos[t];
    if (b == 0 && t == 0) rowptr[NN] = NE;
    for (int i = t; i < n; i += 256) {
        int r = brow[s0 + i] & 31;
        int p = atomicAdd(&pos[r], 1);
        epack[s0 + p] = bcolval[s0 + i];
    }
}

// ---------------- W1 prep: fp32 [512][128] -> bf16 transposed [128][512] ----------------
__global__ __launch_bounds__(256) void prep_w1(const float* __restrict__ W1,
                                               unsigned short* __restrict__ W1t) {
    int t = blockIdx.x * 256 + threadIdx.x;  // 65536 total
    int n = t & 127;
    int k = t >> 7;
    W1t[n * 512 + k] = f2bf(W1[k * 128 + n]);
}

// ---------------- GEMM1 (MFMA): support1(bf16) = x(f32) @ W1 ----------------
__global__ __launch_bounds__(256) void gemm1_mfma(const float* __restrict__ x,
                                                  const unsigned short* __restrict__ W1t,
                                                  unsigned short* __restrict__ out) {
    __shared__ __align__(16) unsigned short As[128 * 32];  // 8 KB, fragment order
    const int tid = threadIdx.x;
    const int lane = tid & 63;
    const int w = __builtin_amdgcn_readfirstlane(tid >> 6);  // wave 0..3 -> cols w*32..+31
    const int quad = lane >> 4;
    const int m = lane & 15;
    const int row0 = blockIdx.x * 128;

    f32x4 acc[8][2];
#pragma unroll
    for (int mt = 0; mt < 8; ++mt)
#pragma unroll
        for (int nt = 0; nt < 2; ++nt) acc[mt][nt] = (f32x4){0.f, 0.f, 0.f, 0.f};

    int srow[4], skq[4];
    const float* sptr[4];
#pragma unroll
    for (int s = 0; s < 4; ++s) {
        int f = tid + s * 256;
        srow[s] = f >> 3;
        skq[s] = f & 7;
        sptr[s] = x + (size_t)(row0 + srow[s]) * FIN + skq[s] * 4;
    }
    float4 ld[4];
#pragma unroll
    for (int s = 0; s < 4; ++s)
        ld[s] = (row0 + srow[s] < NN) ? *(const float4*)sptr[s]
                                      : make_float4(0.f, 0.f, 0.f, 0.f);

    for (int ks = 0; ks < 16; ++ks) {
        __syncthreads();
#pragma unroll
        for (int s = 0; s < 4; ++s) {
            int r = srow[s], kq = skq[s];
            int mt = r >> 4, mm = r & 15;
            int off = mt * 512 + (kq >> 1) * 128 + mm * 8 + (kq & 1) * 4;
            ushort4 p;
            p.x = f2bf(ld[s].x);
            p.y = f2bf(ld[s].y);
            p.z = f2bf(ld[s].z);
            p.w = f2bf(ld[s].w);
            *(ushort4*)&As[off] = p;
        }
        __syncthreads();
        if (ks < 15) {
#pragma unroll
            for (int s = 0; s < 4; ++s)
                ld[s] = (row0 + srow[s] < NN)
                            ? *(const float4*)(sptr[s] + (ks + 1) * 32)
                            : make_float4(0.f, 0.f, 0.f, 0.f);
        }
        bf16x8 bfr[2];
#pragma unroll
        for (int nt = 0; nt < 2; ++nt) {
            int n = (w * 2 + nt) * 16 + m;
            bfr[nt] = *(const bf16x8*)(W1t + (size_t)n * 512 + ks * 32 + quad * 8);
        }
#pragma unroll
        for (int mt = 0; mt < 8; ++mt) {
            bf16x8 af = *(const bf16x8*)&As[mt * 512 + quad * 128 + m * 8];
            acc[mt][0] = __builtin_amdgcn_mfma_f32_16x16x32_bf16(af, bfr[0], acc[mt][0], 0, 0, 0);
            acc[mt][1] = __builtin_amdgcn_mfma_f32_16x16x32_bf16(af, bfr[1], acc[mt][1], 0, 0, 0);
        }
    }
#pragma unroll
    for (int mt = 0; mt < 8; ++mt)
#pragma unroll
        for (int nt = 0; nt < 2; ++nt) {
            int col = (w * 2 + nt) * 16 + m;
#pragma unroll
            for (int r = 0; r < 4; ++r) {
                int row = row0 + mt * 16 + quad * 4 + r;
                if (row < NN) out[(size_t)row * FHID + col] = f2bf(acc[mt][nt][r]);
            }
        }
}

// ---------------- SpMM1 + bias + relu: h(bf16) = relu(A @ support1 + b1) ----------------
__global__ __launch_bounds__(256) void spmm1_kernel(const int* __restrict__ rowptr,
                                                    const int2* __restrict__ epack,
                                                    const unsigned short* __restrict__ dense,
                                                    const float* __restrict__ b1,
                                                    unsigned short* __restrict__ h) {
    const int gtid = blockIdx.x * 256 + threadIdx.x;
    const int wid = gtid >> 6;
    const int lane = threadIdx.x & 63;
    const int half = lane >> 5;
    const int sl = lane & 31;
    const int row = wid * 2 + half;
    const int start = rowptr[row];
    const int cnt = rowptr[row + 1] - start;
    const int maxcnt = max(cnt, __shfl_xor(cnt, 32, 64));
    float4 acc = make_float4(0.f, 0.f, 0.f, 0.f);
    for (int base = 0; base < maxcnt; base += 32) {
        int rem = cnt - base;
        int2 p = make_int2(0, 0);
        if (sl < rem) p = epack[start + base + sl];
        int jn = min(32, maxcnt - base);
        for (int j = 0; j < jn; ++j) {
            int src = half * 32 + j;
            int cj = __shfl(p.x, src, 64);
            float vj = __shfl(__int_as_float(p.y), src, 64);
            uint2 d = *(const uint2*)(dense + (size_t)cj * FHID + sl * 4);
            acc.x += vj * __uint_as_float(d.x << 16);
            acc.y += vj * __uint_as_float(d.x & 0xffff0000u);
            acc.z += vj * __uint_as_float(d.y << 16);
            acc.w += vj * __uint_as_float(d.y & 0xffff0000u);
        }
    }
    float4 bb = ((const float4*)b1)[sl];
    ushort4 o;
    o.x = f2bf(fmaxf(acc.x + bb.x, 0.f));
    o.y = f2bf(fmaxf(acc.y + bb.y, 0.f));
    o.z = f2bf(fmaxf(acc.z + bb.z, 0.f));
    o.w = f2bf(fmaxf(acc.w + bb.w, 0.f));
    *(ushort4*)(h + (size_t)row * FHID + sl * 4) = o;
}

// ---------------- GEMM2: support2(bf16) = h(bf16) @ W2(f32) ----------------
__global__ __launch_bounds__(256) void gemm2_kernel(const unsigned short* __restrict__ h,
                                                    const float* __restrict__ W2,
                                                    unsigned short* __restrict__ out) {
    __shared__ float hs[64][129];
    const int tid = threadIdx.x;
    const int lane = tid & 63;
    const int cg = __builtin_amdgcn_readfirstlane(tid >> 6);
    const int row0 = blockIdx.x * 64;
    const int row = row0 + lane;

    float acc[8];
#pragma unroll
    for (int c = 0; c < 8; ++c) acc[c] = 0.f;

#pragma unroll
    for (int j = 0; j < 8; ++j) {
        int f4 = tid + j * 256;
        int r = f4 >> 5;
        int kq = f4 & 31;
        ushort4 v = make_ushort4(0, 0, 0, 0);
        if (row0 + r < NN) v = *(const ushort4*)(h + (size_t)(row0 + r) * FHID + kq * 4);
        hs[r][kq * 4 + 0] = bf2f(v.x);
        hs[r][kq * 4 + 1] = bf2f(v.y);
        hs[r][kq * 4 + 2] = bf2f(v.z);
        hs[r][kq * 4 + 3] = bf2f(v.w);
    }
    __syncthreads();
#pragma unroll 4
    for (int k = 0; k < FHID; ++k) {
        float a = hs[lane][k];
        const float* wrow = W2 + k * FOUT + cg * 8;
#pragma unroll
        for (int c = 0; c < 8; ++c) acc[c] += a * wrow[c];
    }
    if (row < NN) {
        uint4 st;
        st.x = (unsigned)f2bf(acc[0]) | ((unsigned)f2bf(acc[1]) << 16);
        st.y = (unsigned)f2bf(acc[2]) | ((unsigned)f2bf(acc[3]) << 16);
        st.z = (unsigned)f2bf(acc[4]) | ((unsigned)f2bf(acc[5]) << 16);
        st.w = (unsigned)f2bf(acc[6]) | ((unsigned)f2bf(acc[7]) << 16);
        *(uint4*)(out + (size_t)row * FOUT + cg * 8) = st;
    }
}

// ------- SpMM2 + bias + log_softmax (fp32 out) -------
__global__ __launch_bounds__(256) void spmm2_kernel(const int* __restrict__ rowptr,
                                                    const int2* __restrict__ epack,
                                                    const unsigned short* __restrict__ dense,
                                                    const float* __restrict__ b2,
                                                    float* __restrict__ out) {
    const int gtid = blockIdx.x * 256 + threadIdx.x;
    const int wid = gtid >> 6;
    const int lane = threadIdx.x & 63;
    const int q = lane >> 4;
    const int sl = lane & 15;
    const int row = wid * 4 + q;
    const int start = rowptr[row];
    const int cnt = rowptr[row + 1] - start;
    int m1 = max(cnt, __shfl_xor(cnt, 16, 64));
    const int maxcnt = max(m1, __shfl_xor(m1, 32, 64));
    float2 acc = make_float2(0.f, 0.f);
    for (int base = 0; base < maxcnt; base += 16) {
        int rem = cnt - base;
        int2 p = make_int2(0, 0);
        if (sl < rem) p = epack[start + base + sl];
        int jn = min(16, maxcnt - base);
        for (int j = 0; j < jn; ++j) {
            int src = q * 16 + j;
            int cj = __shfl(p.x, src, 64);
            float vj = __shfl(__int_as_float(p.y), src, 64);
            unsigned d = *(const unsigned*)(dense + (size_t)cj * FOUT + sl * 2);
            acc.x += vj * __uint_as_float(d << 16);
            acc.y += vj * __uint_as_float(d & 0xffff0000u);
        }
    }
    float2 bb = ((const float2*)b2)[sl];
    acc.x += bb.x;
    acc.y += bb.y;
    float m = fmaxf(acc.x, acc.y);
#pragma unroll
    for (int mask = 8; mask >= 1; mask >>= 1) m = fmaxf(m, __shfl_xor(m, mask, 64));
    float ssum = expf(acc.x - m) + expf(acc.y - m);
#pragma unroll
    for (int mask = 8; mask >= 1; mask >>= 1) ssum += __shfl_xor(ssum, mask, 64);
    float lse = m + logf(ssum);
    *(float2*)(out + (size_t)row * FOUT + sl * 2) = make_float2(acc.x - lse, acc.y - lse);
}

extern "C" void kernel_launch(void* const* d_in, const int* in_sizes, int n_in,
                              void* d_out, int out_size, void* d_ws, size_t ws_size,
                              hipStream_t stream) {
    const float* x = (const float*)d_in[0];
    const int* erow = (const int*)d_in[1];
    const int* ecol = (const int*)d_in[2];
    const float* eval = (const float*)d_in[3];
    const float* W1 = (const float*)d_in[4];
    const float* b1 = (const float*)d_in[5];
    const float* W2 = (const float*)d_in[6];
    const float* b2 = (const float*)d_in[7];
    float* out = (float*)d_out;

    char* ws = (char*)d_ws;
    size_t off = 0;
    auto walloc = [&](size_t bytes) -> void* {
        void* p = ws + off;
        off = (off + bytes + 255) & ~(size_t)255;
        return p;
    };
    int2* epack = (int2*)walloc((size_t)NE * 8);            // persists through spmm2
    int* rowptr = (int*)walloc((size_t)(NN + 1) * 4);
    int* bcnt = (int*)walloc((size_t)NBUCK * 4);
    int* bstart = (int*)walloc((size_t)(NBUCK + 1) * 4);
    int* bfill = (int*)walloc((size_t)NBUCK * 4);
    unsigned short* W1t = (unsigned short*)walloc((size_t)FHID * FIN * 2);
    // union region: {brow + bcolval} (CSR build) / {support1 + h} (dense phase).
    // Stream-ordered: CSR kernels finish before gemm1 writes support1 -> safe alias.
    char* uni = (char*)walloc((size_t)NE * 4 + 256 + (size_t)NE * 8);
    int* brow = (int*)uni;
    int2* bcolval = (int2*)(uni + (((size_t)NE * 4 + 255) & ~(size_t)255));
    unsigned short* support1 = (unsigned short*)uni;
    unsigned short* h = (unsigned short*)(uni + (size_t)NN * FHID * 2);
    unsigned short* support2 = support1;  // support1 dead after spmm1

    hipMemsetAsync(bcnt, 0, (size_t)NBUCK * 4, stream);

    prep_w1<<<256, 256, 0, stream>>>(W1, W1t);
    bucket_hist<<<(NE + 255) / 256, 256, 0, stream>>>(erow, bcnt);
    bucket_scan<<<1, 1024, 0, stream>>>(bcnt, bstart, bfill);
    bucket_scatter<<<(NE + 255) / 256, 256, 0, stream>>>(erow, ecol, eval, bfill, brow, bcolval);
    bucket_to_csr<<<NBUCK, 256, 0, stream>>>(bstart, brow, bcolval, rowptr, epack);

    gemm1_mfma<<<(NN + 127) / 128, 256, 0, stream>>>(x, W1t, support1);
    spmm1_kernel<<<NN / 8, 256, 0, stream>>>(rowptr, epack, support1, b1, h);
    gemm2_kernel<<<(NN + 63) / 64, 256, 0, stream>>>(h, W2, support2);
    spmm2_kernel<<<NN / 16, 256, 0, stream>>>(rowptr, epack, support2, b2, out);
}

// Round 4
// 688.110 us; speedup vs baseline: 1.6283x; 1.6283x over previous
//
#include <hip/hip_runtime.h>

// GCN forward on MI355X — bf16 intermediate pipeline.
//
// CSR build: per-workgroup bucket hist -> flat scan -> partition-private
// scatter -> per-bucket finalize. Rationale (R3 post-mortem): any scatter
// whose output position comes from a device-scope atomic interleaves
// consecutive line entries across all 8 XCDs; non-coherent per-XCD L2s each
// write back the partial 64B line -> ~8x HBM write amplification (measured
// 246 MB for 25.6 MB payload). Fix = exclusive line ownership: each
// (bucket, workgroup) cell is a private contiguous range (avg 262 B), and
// the per-bucket finalize window (~65 KB) is owned by one workgroup.

#define NN 100000
#define NE 3200000
#define FIN 512
#define FHID 128
#define FOUT 32
#define BROWS 256          // rows per bucket
#define NBUCK 391          // ceil(NN/256)
#define NPART 256          // scatter partitions (workgroups)
#define CHUNK 12800        // edges per partition; NPART*CHUNK >= NE
#define TOT (NBUCK * NPART)  // 100096 counter cells
#define NSCAN1 98          // ceil(TOT/1024)

typedef __attribute__((ext_vector_type(8))) short bf16x8;
typedef __attribute__((ext_vector_type(4))) float f32x4;

static __device__ __forceinline__ unsigned short f2bf(float f) {
    unsigned u = __float_as_uint(f);
    unsigned r = (u + 0x7FFFu + ((u >> 16) & 1u)) >> 16;  // RTN-even
    return (unsigned short)r;
}
static __device__ __forceinline__ float bf2f(unsigned short u) {
    return __uint_as_float(((unsigned)u) << 16);
}

// ---------------- CSR build ----------------
// Phase A: per-partition bucket histogram. cntG layout: [part][bucket]
// (contiguous per partition -> exclusive write lines).
__global__ __launch_bounds__(256) void hist_part(const int* __restrict__ erow,
                                                 int* __restrict__ cntG) {
    __shared__ int c[NBUCK];
    const int t = threadIdx.x;
    const int w = blockIdx.x;
    for (int i = t; i < NBUCK; i += 256) c[i] = 0;
    __syncthreads();
    const int e0 = w * CHUNK;
    const int e1 = min(e0 + CHUNK, NE);
    for (int e = e0 + t; e < e1; e += 256) atomicAdd(&c[erow[e] >> 8], 1);
    __syncthreads();
    for (int i = t; i < NBUCK; i += 256) cntG[w * NBUCK + i] = c[i];
}

// Phase B: flat exclusive scan over TOT cells in (bucket, part) order.
// Reads cntG transposed (gather, L2-resident); writes off flat (clean).
__global__ __launch_bounds__(256) void scan1_kernel(const int* __restrict__ cntG,
                                                    int* __restrict__ off,
                                                    int* __restrict__ partials) {
    __shared__ int s[256];
    int t = threadIdx.x;
    int i0 = blockIdx.x * 1024 + t * 4;
    int v[4];
#pragma unroll
    for (int j = 0; j < 4; ++j) {
        int i = i0 + j;
        v[j] = (i < TOT) ? cntG[(i & (NPART - 1)) * NBUCK + (i >> 8)] : 0;
    }
    int lsum = v[0] + v[1] + v[2] + v[3];
    s[t] = lsum;
    __syncthreads();
    for (int o = 1; o < 256; o <<= 1) {
        int xv = (t >= o) ? s[t - o] : 0;
        __syncthreads();
        s[t] += xv;
        __syncthreads();
    }
    if (t == 255) partials[blockIdx.x] = s[255];
    int run = s[t] - lsum;
#pragma unroll
    for (int j = 0; j < 4; ++j) {
        if (i0 + j < TOT) off[i0 + j] = run;
        run += v[j];
    }
}

__global__ void scan2_kernel(int* partials) {
    __shared__ int s[128];
    int t = threadIdx.x;
    int v = (t < NSCAN1) ? partials[t] : 0;
    s[t] = v;
    __syncthreads();
    for (int o = 1; o < 128; o <<= 1) {
        int xv = (t >= o) ? s[t - o] : 0;
        __syncthreads();
        s[t] += xv;
        __syncthreads();
    }
    if (t < NSCAN1) partials[t] = s[t] - v;
}

__global__ __launch_bounds__(256) void scan3_kernel(int* __restrict__ off,
                                                    const int* __restrict__ partials) {
    int add = partials[blockIdx.x];
    int i0 = blockIdx.x * 1024 + threadIdx.x * 4;
#pragma unroll
    for (int j = 0; j < 4; ++j)
        if (i0 + j < TOT) off[i0 + j] += add;
}

__global__ void make_bstart(const int* __restrict__ off, int* __restrict__ bstart) {
    int t = blockIdx.x * 256 + threadIdx.x;
    if (t < NBUCK) bstart[t] = off[t * NPART];
    if (t == 0) bstart[NBUCK] = NE;
}

// Phase C: partition-private scatter. Each (bucket,part) range is exclusively
// owned by this workgroup -> ~1.2x write amplification instead of ~8x.
// Packs rowLocal (8b) into bits 20..27 of .x (col < 2^17).
__global__ __launch_bounds__(256) void scatter_part(const int* __restrict__ erow,
                                                    const int* __restrict__ ecol,
                                                    const float* __restrict__ eval,
                                                    const int* __restrict__ off,
                                                    int2* __restrict__ bcolval) {
    __shared__ int pos[NBUCK];
    const int t = threadIdx.x;
    const int w = blockIdx.x;
    for (int b = t; b < NBUCK; b += 256) pos[b] = off[b * NPART + w];
    __syncthreads();
    const int e0 = w * CHUNK;
    const int e1 = min(e0 + CHUNK, NE);
    for (int e = e0 + t; e < e1; e += 256) {
        int r = erow[e];
        int idx = atomicAdd(&pos[r >> 8], 1);
        bcolval[idx] = make_int2(ecol[e] | ((r & 255) << 20), __float_as_int(eval[e]));
    }
}

// Phase D: per-bucket finalize to row-sorted CSR. Window (~65 KB) owned by
// one workgroup; scatter writes confined to it.
__global__ __launch_bounds__(256) void bucket_to_csr(const int* __restrict__ bstart,
                                                     const int2* __restrict__ bcolval,
                                                     int* __restrict__ rowptr,
                                                     int2* __restrict__ epack) {
    __shared__ int cnt[256];
    __shared__ int pos[256];
    __shared__ int s[256];
    const int b = blockIdx.x;
    const int t = threadIdx.x;
    const int s0 = bstart[b];
    const int n = bstart[b + 1] - s0;
    cnt[t] = 0;
    __syncthreads();
    for (int i = t; i < n; i += 256)
        atomicAdd(&cnt[((unsigned)bcolval[s0 + i].x) >> 20], 1);
    __syncthreads();
    int myc = cnt[t];
    s[t] = myc;
    __syncthreads();
    for (int o = 1; o < 256; o <<= 1) {
        int xv = (t >= o) ? s[t - o] : 0;
        __syncthreads();
        s[t] += xv;
        __syncthreads();
    }
    int excl = s[t] - myc;
    pos[t] = excl;
    int row = b * BROWS + t;
    if (row < NN) rowptr[row] = s0 + excl;
    if (b == 0 && t == 0) rowptr[NN] = NE;
    __syncthreads();
    for (int i = t; i < n; i += 256) {
        int2 v = bcolval[s0 + i];
        int p = atomicAdd(&pos[((unsigned)v.x) >> 20], 1);
        epack[s0 + p] = make_int2(v.x & 0xFFFFF, v.y);
    }
}

// ---------------- W1 prep: fp32 [512][128] -> bf16 transposed [128][512] ----------------
__global__ __launch_bounds__(256) void prep_w1(const float* __restrict__ W1,
                                               unsigned short* __restrict__ W1t) {
    int t = blockIdx.x * 256 + threadIdx.x;  // 65536 total
    int n = t & 127;
    int k = t >> 7;
    W1t[n * 512 + k] = f2bf(W1[k * 128 + n]);
}

// ---------------- GEMM1 (MFMA): support1(bf16) = x(f32) @ W1 ----------------
__global__ __launch_bounds__(256) void gemm1_mfma(const float* __restrict__ x,
                                                  const unsigned short* __restrict__ W1t,
                                                  unsigned short* __restrict__ out) {
    __shared__ __align__(16) unsigned short As[128 * 32];  // 8 KB, fragment order
    const int tid = threadIdx.x;
    const int lane = tid & 63;
    const int w = __builtin_amdgcn_readfirstlane(tid >> 6);
    const int quad = lane >> 4;
    const int m = lane & 15;
    const int row0 = blockIdx.x * 128;

    f32x4 acc[8][2];
#pragma unroll
    for (int mt = 0; mt < 8; ++mt)
#pragma unroll
        for (int nt = 0; nt < 2; ++nt) acc[mt][nt] = (f32x4){0.f, 0.f, 0.f, 0.f};

    int srow[4], skq[4];
    const float* sptr[4];
#pragma unroll
    for (int s = 0; s < 4; ++s) {
        int f = tid + s * 256;
        srow[s] = f >> 3;
        skq[s] = f & 7;
        sptr[s] = x + (size_t)(row0 + srow[s]) * FIN + skq[s] * 4;
    }
    float4 ld[4];
#pragma unroll
    for (int s = 0; s < 4; ++s)
        ld[s] = (row0 + srow[s] < NN) ? *(const float4*)sptr[s]
                                      : make_float4(0.f, 0.f, 0.f, 0.f);

    for (int ks = 0; ks < 16; ++ks) {
        __syncthreads();
#pragma unroll
        for (int s = 0; s < 4; ++s) {
            int r = srow[s], kq = skq[s];
            int mt = r >> 4, mm = r & 15;
            int off = mt * 512 + (kq >> 1) * 128 + mm * 8 + (kq & 1) * 4;
            ushort4 p;
            p.x = f2bf(ld[s].x);
            p.y = f2bf(ld[s].y);
            p.z = f2bf(ld[s].z);
            p.w = f2bf(ld[s].w);
            *(ushort4*)&As[off] = p;
        }
        __syncthreads();
        if (ks < 15) {
#pragma unroll
            for (int s = 0; s < 4; ++s)
                ld[s] = (row0 + srow[s] < NN)
                            ? *(const float4*)(sptr[s] + (ks + 1) * 32)
                            : make_float4(0.f, 0.f, 0.f, 0.f);
        }
        bf16x8 bfr[2];
#pragma unroll
        for (int nt = 0; nt < 2; ++nt) {
            int n = (w * 2 + nt) * 16 + m;
            bfr[nt] = *(const bf16x8*)(W1t + (size_t)n * 512 + ks * 32 + quad * 8);
        }
#pragma unroll
        for (int mt = 0; mt < 8; ++mt) {
            bf16x8 af = *(const bf16x8*)&As[mt * 512 + quad * 128 + m * 8];
            acc[mt][0] = __builtin_amdgcn_mfma_f32_16x16x32_bf16(af, bfr[0], acc[mt][0], 0, 0, 0);
            acc[mt][1] = __builtin_amdgcn_mfma_f32_16x16x32_bf16(af, bfr[1], acc[mt][1], 0, 0, 0);
        }
    }
#pragma unroll
    for (int mt = 0; mt < 8; ++mt)
#pragma unroll
        for (int nt = 0; nt < 2; ++nt) {
            int col = (w * 2 + nt) * 16 + m;
#pragma unroll
            for (int r = 0; r < 4; ++r) {
                int row = row0 + mt * 16 + quad * 4 + r;
                if (row < NN) out[(size_t)row * FHID + col] = f2bf(acc[mt][nt][r]);
            }
        }
}

// ---------------- SpMM1 + bias + relu: h(bf16) = relu(A @ support1 + b1) ----------------
__global__ __launch_bounds__(256) void spmm1_kernel(const int* __restrict__ rowptr,
                                                    const int2* __restrict__ epack,
                                                    const unsigned short* __restrict__ dense,
                                                    const float* __restrict__ b1,
                                                    unsigned short* __restrict__ h) {
    const int gtid = blockIdx.x * 256 + threadIdx.x;
    const int wid = gtid >> 6;
    const int lane = threadIdx.x & 63;
    const int half = lane >> 5;
    const int sl = lane & 31;
    const int row = wid * 2 + half;
    const int start = rowptr[row];
    const int cnt = rowptr[row + 1] - start;
    const int maxcnt = max(cnt, __shfl_xor(cnt, 32, 64));
    float4 acc = make_float4(0.f, 0.f, 0.f, 0.f);
    for (int base = 0; base < maxcnt; base += 32) {
        int rem = cnt - base;
        int2 p = make_int2(0, 0);
        if (sl < rem) p = epack[start + base + sl];
        int jn = min(32, maxcnt - base);
        for (int j = 0; j < jn; ++j) {
            int src = half * 32 + j;
            int cj = __shfl(p.x, src, 64);
            float vj = __shfl(__int_as_float(p.y), src, 64);
            uint2 d = *(const uint2*)(dense + (size_t)cj * FHID + sl * 4);
            acc.x += vj * __uint_as_float(d.x << 16);
            acc.y += vj * __uint_as_float(d.x & 0xffff0000u);
            acc.z += vj * __uint_as_float(d.y << 16);
            acc.w += vj * __uint_as_float(d.y & 0xffff0000u);
        }
    }
    float4 bb = ((const float4*)b1)[sl];
    ushort4 o;
    o.x = f2bf(fmaxf(acc.x + bb.x, 0.f));
    o.y = f2bf(fmaxf(acc.y + bb.y, 0.f));
    o.z = f2bf(fmaxf(acc.z + bb.z, 0.f));
    o.w = f2bf(fmaxf(acc.w + bb.w, 0.f));
    *(ushort4*)(h + (size_t)row * FHID + sl * 4) = o;
}

// ---------------- GEMM2: support2(bf16) = h(bf16) @ W2(f32) ----------------
__global__ __launch_bounds__(256) void gemm2_kernel(const unsigned short* __restrict__ h,
                                                    const float* __restrict__ W2,
                                                    unsigned short* __restrict__ out) {
    __shared__ float hs[64][129];
    const int tid = threadIdx.x;
    const int lane = tid & 63;
    const int cg = __builtin_amdgcn_readfirstlane(tid >> 6);
    const int row0 = blockIdx.x * 64;
    const int row = row0 + lane;

    float acc[8];
#pragma unroll
    for (int c = 0; c < 8; ++c) acc[c] = 0.f;

#pragma unroll
    for (int j = 0; j < 8; ++j) {
        int f4 = tid + j * 256;
        int r = f4 >> 5;
        int kq = f4 & 31;
        ushort4 v = make_ushort4(0, 0, 0, 0);
        if (row0 + r < NN) v = *(const ushort4*)(h + (size_t)(row0 + r) * FHID + kq * 4);
        hs[r][kq * 4 + 0] = bf2f(v.x);
        hs[r][kq * 4 + 1] = bf2f(v.y);
        hs[r][kq * 4 + 2] = bf2f(v.z);
        hs[r][kq * 4 + 3] = bf2f(v.w);
    }
    __syncthreads();
#pragma unroll 4
    for (int k = 0; k < FHID; ++k) {
        float a = hs[lane][k];
        const float* wrow = W2 + k * FOUT + cg * 8;
#pragma unroll
        for (int c = 0; c < 8; ++c) acc[c] += a * wrow[c];
    }
    if (row < NN) {
        uint4 st;
        st.x = (unsigned)f2bf(acc[0]) | ((unsigned)f2bf(acc[1]) << 16);
        st.y = (unsigned)f2bf(acc[2]) | ((unsigned)f2bf(acc[3]) << 16);
        st.z = (unsigned)f2bf(acc[4]) | ((unsigned)f2bf(acc[5]) << 16);
        st.w = (unsigned)f2bf(acc[6]) | ((unsigned)f2bf(acc[7]) << 16);
        *(uint4*)(out + (size_t)row * FOUT + cg * 8) = st;
    }
}

// ------- SpMM2 + bias + log_softmax (fp32 out) -------
__global__ __launch_bounds__(256) void spmm2_kernel(const int* __restrict__ rowptr,
                                                    const int2* __restrict__ epack,
                                                    const unsigned short* __restrict__ dense,
                                                    const float* __restrict__ b2,
                                                    float* __restrict__ out) {
    const int gtid = blockIdx.x * 256 + threadIdx.x;
    const int wid = gtid >> 6;
    const int lane = threadIdx.x & 63;
    const int q = lane >> 4;
    const int sl = lane & 15;
    const int row = wid * 4 + q;
    const int start = rowptr[row];
    const int cnt = rowptr[row + 1] - start;
    int m1 = max(cnt, __shfl_xor(cnt, 16, 64));
    const int maxcnt = max(m1, __shfl_xor(m1, 32, 64));
    float2 acc = make_float2(0.f, 0.f);
    for (int base = 0; base < maxcnt; base += 16) {
        int rem = cnt - base;
        int2 p = make_int2(0, 0);
        if (sl < rem) p = epack[start + base + sl];
        int jn = min(16, maxcnt - base);
        for (int j = 0; j < jn; ++j) {
            int src = q * 16 + j;
            int cj = __shfl(p.x, src, 64);
            float vj = __shfl(__int_as_float(p.y), src, 64);
            unsigned d = *(const unsigned*)(dense + (size_t)cj * FOUT + sl * 2);
            acc.x += vj * __uint_as_float(d << 16);
            acc.y += vj * __uint_as_float(d & 0xffff0000u);
        }
    }
    float2 bb = ((const float2*)b2)[sl];
    acc.x += bb.x;
    acc.y += bb.y;
    float m = fmaxf(acc.x, acc.y);
#pragma unroll
    for (int mask = 8; mask >= 1; mask >>= 1) m = fmaxf(m, __shfl_xor(m, mask, 64));
    float ssum = expf(acc.x - m) + expf(acc.y - m);
#pragma unroll
    for (int mask = 8; mask >= 1; mask >>= 1) ssum += __shfl_xor(ssum, mask, 64);
    float lse = m + logf(ssum);
    *(float2*)(out + (size_t)row * FOUT + sl * 2) = make_float2(acc.x - lse, acc.y - lse);
}

extern "C" void kernel_launch(void* const* d_in, const int* in_sizes, int n_in,
                              void* d_out, int out_size, void* d_ws, size_t ws_size,
                              hipStream_t stream) {
    const float* x = (const float*)d_in[0];
    const int* erow = (const int*)d_in[1];
    const int* ecol = (const int*)d_in[2];
    const float* eval = (const float*)d_in[3];
    const float* W1 = (const float*)d_in[4];
    const float* b1 = (const float*)d_in[5];
    const float* W2 = (const float*)d_in[6];
    const float* b2 = (const float*)d_in[7];
    float* out = (float*)d_out;

    char* ws = (char*)d_ws;
    size_t off_b = 0;
    auto walloc = [&](size_t bytes) -> void* {
        void* p = ws + off_b;
        off_b = (off_b + bytes + 255) & ~(size_t)255;
        return p;
    };
    int2* epack = (int2*)walloc((size_t)NE * 8);  // persists through spmm2
    int* rowptr = (int*)walloc((size_t)(NN + 1) * 4);
    int* cntG = (int*)walloc((size_t)TOT * 4);
    int* off = (int*)walloc((size_t)TOT * 4);
    int* bstart = (int*)walloc((size_t)(NBUCK + 1) * 4);
    int* partials = (int*)walloc(4096);
    unsigned short* W1t = (unsigned short*)walloc((size_t)FHID * FIN * 2);
    // union: bcolval (CSR build, 25.6 MB) / support1+h (dense phase, 51.2 MB).
    // Stream-ordered: bucket_to_csr finishes before gemm1 writes support1.
    char* uni = (char*)walloc((size_t)NN * FHID * 2 * 2);
    int2* bcolval = (int2*)uni;
    unsigned short* support1 = (unsigned short*)uni;
    unsigned short* h = (unsigned short*)(uni + (size_t)NN * FHID * 2);
    unsigned short* support2 = support1;  // support1 dead after spmm1

    prep_w1<<<256, 256, 0, stream>>>(W1, W1t);
    hist_part<<<NPART, 256, 0, stream>>>(erow, cntG);
    scan1_kernel<<<NSCAN1, 256, 0, stream>>>(cntG, off, partials);
    scan2_kernel<<<1, 128, 0, stream>>>(partials);
    scan3_kernel<<<NSCAN1, 256, 0, stream>>>(off, partials);
    make_bstart<<<2, 256, 0, stream>>>(off, bstart);
    scatter_part<<<NPART, 256, 0, stream>>>(erow, ecol, eval, off, bcolval);
    bucket_to_csr<<<NBUCK, 256, 0, stream>>>(bstart, bcolval, rowptr, epack);

    gemm1_mfma<<<(NN + 127) / 128, 256, 0, stream>>>(x, W1t, support1);
    spmm1_kernel<<<NN / 8, 256, 0, stream>>>(rowptr, epack, support1, b1, h);
    gemm2_kernel<<<(NN + 63) / 64, 256, 0, stream>>>(h, W2, support2);
    spmm2_kernel<<<NN / 16, 256, 0, stream>>>(rowptr, epack, support2, b2, out);
}

// Round 5
// 648.148 us; speedup vs baseline: 1.7287x; 1.0617x over previous
//
#include <hip/hip_runtime.h>

// GCN forward on MI355X — bf16 intermediate pipeline.
//
// CSR build: per-workgroup bucket hist -> flat scan -> partition-private
// scatter -> per-bucket finalize (exclusive 64B-line ownership per writer;
// device-scope-atomic-indexed scatter measured 8x HBM write amplification
// from cross-XCD partial-line writebacks).
//
// SpMM: pull-form CSR, subgroup-per-row with grouped unroll-by-4 gathers
// (R4 post-mortem: 31% VALUBusy at 38% HBM = latency/MLP-bound, not BW).

#define NN 100000
#define NE 3200000
#define FIN 512
#define FHID 128
#define FOUT 32
#define BROWS 256          // rows per bucket
#define NBUCK 391          // ceil(NN/256)
#define NPART 256          // scatter partitions (workgroups)
#define CHUNK 12800        // edges per partition; NPART*CHUNK >= NE
#define TOT (NBUCK * NPART)  // 100096 counter cells
#define NSCAN1 98          // ceil(TOT/1024)

typedef __attribute__((ext_vector_type(8))) short bf16x8;
typedef __attribute__((ext_vector_type(4))) float f32x4;

static __device__ __forceinline__ unsigned short f2bf(float f) {
    unsigned u = __float_as_uint(f);
    unsigned r = (u + 0x7FFFu + ((u >> 16) & 1u)) >> 16;  // RTN-even
    return (unsigned short)r;
}
static __device__ __forceinline__ float bf2f(unsigned short u) {
    return __uint_as_float(((unsigned)u) << 16);
}
static __device__ __forceinline__ float bflo(unsigned u) {
    return __uint_as_float(u << 16);
}
static __device__ __forceinline__ float bfhi(unsigned u) {
    return __uint_as_float(u & 0xffff0000u);
}

// ---------------- CSR build ----------------
__global__ __launch_bounds__(256) void hist_part(const int* __restrict__ erow,
                                                 int* __restrict__ cntG) {
    __shared__ int c[NBUCK];
    const int t = threadIdx.x;
    const int w = blockIdx.x;
    for (int i = t; i < NBUCK; i += 256) c[i] = 0;
    __syncthreads();
    const int e0 = w * CHUNK;
    const int e1 = min(e0 + CHUNK, NE);
    for (int e = e0 + t; e < e1; e += 256) atomicAdd(&c[erow[e] >> 8], 1);
    __syncthreads();
    for (int i = t; i < NBUCK; i += 256) cntG[w * NBUCK + i] = c[i];
}

__global__ __launch_bounds__(256) void scan1_kernel(const int* __restrict__ cntG,
                                                    int* __restrict__ off,
                                                    int* __restrict__ partials) {
    __shared__ int s[256];
    int t = threadIdx.x;
    int i0 = blockIdx.x * 1024 + t * 4;
    int v[4];
#pragma unroll
    for (int j = 0; j < 4; ++j) {
        int i = i0 + j;
        v[j] = (i < TOT) ? cntG[(i & (NPART - 1)) * NBUCK + (i >> 8)] : 0;
    }
    int lsum = v[0] + v[1] + v[2] + v[3];
    s[t] = lsum;
    __syncthreads();
    for (int o = 1; o < 256; o <<= 1) {
        int xv = (t >= o) ? s[t - o] : 0;
        __syncthreads();
        s[t] += xv;
        __syncthreads();
    }
    if (t == 255) partials[blockIdx.x] = s[255];
    int run = s[t] - lsum;
#pragma unroll
    for (int j = 0; j < 4; ++j) {
        if (i0 + j < TOT) off[i0 + j] = run;
        run += v[j];
    }
}

__global__ void scan2_kernel(int* partials) {
    __shared__ int s[128];
    int t = threadIdx.x;
    int v = (t < NSCAN1) ? partials[t] : 0;
    s[t] = v;
    __syncthreads();
    for (int o = 1; o < 128; o <<= 1) {
        int xv = (t >= o) ? s[t - o] : 0;
        __syncthreads();
        s[t] += xv;
        __syncthreads();
    }
    if (t < NSCAN1) partials[t] = s[t] - v;
}

__global__ __launch_bounds__(256) void scan3_kernel(int* __restrict__ off,
                                                    const int* __restrict__ partials) {
    int add = partials[blockIdx.x];
    int i0 = blockIdx.x * 1024 + threadIdx.x * 4;
#pragma unroll
    for (int j = 0; j < 4; ++j)
        if (i0 + j < TOT) off[i0 + j] += add;
}

__global__ void make_bstart(const int* __restrict__ off, int* __restrict__ bstart) {
    int t = blockIdx.x * 256 + threadIdx.x;
    if (t < NBUCK) bstart[t] = off[t * NPART];
    if (t == 0) bstart[NBUCK] = NE;
}

__global__ __launch_bounds__(256) void scatter_part(const int* __restrict__ erow,
                                                    const int* __restrict__ ecol,
                                                    const float* __restrict__ eval,
                                                    const int* __restrict__ off,
                                                    int2* __restrict__ bcolval) {
    __shared__ int pos[NBUCK];
    const int t = threadIdx.x;
    const int w = blockIdx.x;
    for (int b = t; b < NBUCK; b += 256) pos[b] = off[b * NPART + w];
    __syncthreads();
    const int e0 = w * CHUNK;
    const int e1 = min(e0 + CHUNK, NE);
    for (int e = e0 + t; e < e1; e += 256) {
        int r = erow[e];
        int idx = atomicAdd(&pos[r >> 8], 1);
        bcolval[idx] = make_int2(ecol[e] | ((r & 255) << 20), __float_as_int(eval[e]));
    }
}

__global__ __launch_bounds__(256) void bucket_to_csr(const int* __restrict__ bstart,
                                                     const int2* __restrict__ bcolval,
                                                     int* __restrict__ rowptr,
                                                     int2* __restrict__ epack) {
    __shared__ int cnt[256];
    __shared__ int pos[256];
    __shared__ int s[256];
    const int b = blockIdx.x;
    const int t = threadIdx.x;
    const int s0 = bstart[b];
    const int n = bstart[b + 1] - s0;
    cnt[t] = 0;
    __syncthreads();
    for (int i = t; i < n; i += 256)
        atomicAdd(&cnt[((unsigned)bcolval[s0 + i].x) >> 20], 1);
    __syncthreads();
    int myc = cnt[t];
    s[t] = myc;
    __syncthreads();
    for (int o = 1; o < 256; o <<= 1) {
        int xv = (t >= o) ? s[t - o] : 0;
        __syncthreads();
        s[t] += xv;
        __syncthreads();
    }
    int excl = s[t] - myc;
    pos[t] = excl;
    int row = b * BROWS + t;
    if (row < NN) rowptr[row] = s0 + excl;
    if (b == 0 && t == 0) rowptr[NN] = NE;
    __syncthreads();
    for (int i = t; i < n; i += 256) {
        int2 v = bcolval[s0 + i];
        int p = atomicAdd(&pos[((unsigned)v.x) >> 20], 1);
        epack[s0 + p] = make_int2(v.x & 0xFFFFF, v.y);
    }
}

// ---------------- W1 prep ----------------
__global__ __launch_bounds__(256) void prep_w1(const float* __restrict__ W1,
                                               unsigned short* __restrict__ W1t) {
    int t = blockIdx.x * 256 + threadIdx.x;
    int n = t & 127;
    int k = t >> 7;
    W1t[n * 512 + k] = f2bf(W1[k * 128 + n]);
}

// ---------------- GEMM1 (MFMA): support1(bf16) = x(f32) @ W1 ----------------
__global__ __launch_bounds__(256) void gemm1_mfma(const float* __restrict__ x,
                                                  const unsigned short* __restrict__ W1t,
                                                  unsigned short* __restrict__ out) {
    __shared__ __align__(16) unsigned short As[128 * 32];
    const int tid = threadIdx.x;
    const int lane = tid & 63;
    const int w = __builtin_amdgcn_readfirstlane(tid >> 6);
    const int quad = lane >> 4;
    const int m = lane & 15;
    const int row0 = blockIdx.x * 128;

    f32x4 acc[8][2];
#pragma unroll
    for (int mt = 0; mt < 8; ++mt)
#pragma unroll
        for (int nt = 0; nt < 2; ++nt) acc[mt][nt] = (f32x4){0.f, 0.f, 0.f, 0.f};

    int srow[4], skq[4];
    const float* sptr[4];
#pragma unroll
    for (int s = 0; s < 4; ++s) {
        int f = tid + s * 256;
        srow[s] = f >> 3;
        skq[s] = f & 7;
        sptr[s] = x + (size_t)(row0 + srow[s]) * FIN + skq[s] * 4;
    }
    float4 ld[4];
#pragma unroll
    for (int s = 0; s < 4; ++s)
        ld[s] = (row0 + srow[s] < NN) ? *(const float4*)sptr[s]
                                      : make_float4(0.f, 0.f, 0.f, 0.f);

    for (int ks = 0; ks < 16; ++ks) {
        __syncthreads();
#pragma unroll
        for (int s = 0; s < 4; ++s) {
            int r = srow[s], kq = skq[s];
            int mt = r >> 4, mm = r & 15;
            int off = mt * 512 + (kq >> 1) * 128 + mm * 8 + (kq & 1) * 4;
            ushort4 p;
            p.x = f2bf(ld[s].x);
            p.y = f2bf(ld[s].y);
            p.z = f2bf(ld[s].z);
            p.w = f2bf(ld[s].w);
            *(ushort4*)&As[off] = p;
        }
        __syncthreads();
        if (ks < 15) {
#pragma unroll
            for (int s = 0; s < 4; ++s)
                ld[s] = (row0 + srow[s] < NN)
                            ? *(const float4*)(sptr[s] + (ks + 1) * 32)
                            : make_float4(0.f, 0.f, 0.f, 0.f);
        }
        bf16x8 bfr[2];
#pragma unroll
        for (int nt = 0; nt < 2; ++nt) {
            int n = (w * 2 + nt) * 16 + m;
            bfr[nt] = *(const bf16x8*)(W1t + (size_t)n * 512 + ks * 32 + quad * 8);
        }
#pragma unroll
        for (int mt = 0; mt < 8; ++mt) {
            bf16x8 af = *(const bf16x8*)&As[mt * 512 + quad * 128 + m * 8];
            acc[mt][0] = __builtin_amdgcn_mfma_f32_16x16x32_bf16(af, bfr[0], acc[mt][0], 0, 0, 0);
            acc[mt][1] = __builtin_amdgcn_mfma_f32_16x16x32_bf16(af, bfr[1], acc[mt][1], 0, 0, 0);
        }
    }
#pragma unroll
    for (int mt = 0; mt < 8; ++mt)
#pragma unroll
        for (int nt = 0; nt < 2; ++nt) {
            int col = (w * 2 + nt) * 16 + m;
#pragma unroll
            for (int r = 0; r < 4; ++r) {
                int row = row0 + mt * 16 + quad * 4 + r;
                if (row < NN) out[(size_t)row * FHID + col] = f2bf(acc[mt][nt][r]);
            }
        }
}

// ---------------- SpMM1 + bias + relu: h(bf16) = relu(A @ support1 + b1) ----------------
// Quarter-wave per row (16 lanes x uint4 = 256B), 4 rows/wave, 16 rows/block.
// Inner loop grouped x4: 8 shfl -> 4 independent dwordx4 gathers -> 32 FMA.
__global__ __launch_bounds__(256) void spmm1_kernel(const int* __restrict__ rowptr,
                                                    const int2* __restrict__ epack,
                                                    const unsigned short* __restrict__ dense,
                                                    const float* __restrict__ b1,
                                                    unsigned short* __restrict__ h) {
    const int gtid = blockIdx.x * 256 + threadIdx.x;
    const int wid = gtid >> 6;
    const int lane = threadIdx.x & 63;
    const int q = lane >> 4;   // 0..3
    const int sl = lane & 15;  // 0..15
    const int row = wid * 4 + q;  // grid exact: NN/16 blocks
    const int start = rowptr[row];
    const int cnt = rowptr[row + 1] - start;
    float acc[8];
#pragma unroll
    for (int i = 0; i < 8; ++i) acc[i] = 0.f;

    for (int base = 0; base < cnt; base += 16) {
        const int rem = cnt - base;
        int2 p = make_int2(0, 0);
        if (sl < rem) p = epack[start + base + sl];
        const int jn = min(16, rem);
        for (int j = 0; j < jn; j += 4) {
            int cj[4];
            float vj[4];
            uint4 d[4];
#pragma unroll
            for (int k = 0; k < 4; ++k) {
                cj[k] = __shfl(p.x, q * 16 + j + k, 64);
                vj[k] = __shfl(__int_as_float(p.y), q * 16 + j + k, 64);
            }
#pragma unroll
            for (int k = 0; k < 4; ++k)
                d[k] = *(const uint4*)(dense + (size_t)cj[k] * FHID + sl * 8);
#pragma unroll
            for (int k = 0; k < 4; ++k) {
                acc[0] += vj[k] * bflo(d[k].x);
                acc[1] += vj[k] * bfhi(d[k].x);
                acc[2] += vj[k] * bflo(d[k].y);
                acc[3] += vj[k] * bfhi(d[k].y);
                acc[4] += vj[k] * bflo(d[k].z);
                acc[5] += vj[k] * bfhi(d[k].z);
                acc[6] += vj[k] * bflo(d[k].w);
                acc[7] += vj[k] * bfhi(d[k].w);
            }
        }
    }
    float4 bb0 = *(const float4*)(b1 + sl * 8);
    float4 bb1 = *(const float4*)(b1 + sl * 8 + 4);
    uint4 st;
    st.x = (unsigned)f2bf(fmaxf(acc[0] + bb0.x, 0.f)) |
           ((unsigned)f2bf(fmaxf(acc[1] + bb0.y, 0.f)) << 16);
    st.y = (unsigned)f2bf(fmaxf(acc[2] + bb0.z, 0.f)) |
           ((unsigned)f2bf(fmaxf(acc[3] + bb0.w, 0.f)) << 16);
    st.z = (unsigned)f2bf(fmaxf(acc[4] + bb1.x, 0.f)) |
           ((unsigned)f2bf(fmaxf(acc[5] + bb1.y, 0.f)) << 16);
    st.w = (unsigned)f2bf(fmaxf(acc[6] + bb1.z, 0.f)) |
           ((unsigned)f2bf(fmaxf(acc[7] + bb1.w, 0.f)) << 16);
    *(uint4*)(h + (size_t)row * FHID + sl * 8) = st;
}

// ---------------- GEMM2: support2(bf16) = h(bf16) @ W2(f32) ----------------
__global__ __launch_bounds__(256) void gemm2_kernel(const unsigned short* __restrict__ h,
                                                    const float* __restrict__ W2,
                                                    unsigned short* __restrict__ out) {
    __shared__ float hs[64][129];
    const int tid = threadIdx.x;
    const int lane = tid & 63;
    const int cg = __builtin_amdgcn_readfirstlane(tid >> 6);
    const int row0 = blockIdx.x * 64;
    const int row = row0 + lane;

    float acc[8];
#pragma unroll
    for (int c = 0; c < 8; ++c) acc[c] = 0.f;

#pragma unroll
    for (int j = 0; j < 8; ++j) {
        int f4 = tid + j * 256;
        int r = f4 >> 5;
        int kq = f4 & 31;
        ushort4 v = make_ushort4(0, 0, 0, 0);
        if (row0 + r < NN) v = *(const ushort4*)(h + (size_t)(row0 + r) * FHID + kq * 4);
        hs[r][kq * 4 + 0] = bf2f(v.x);
        hs[r][kq * 4 + 1] = bf2f(v.y);
        hs[r][kq * 4 + 2] = bf2f(v.z);
        hs[r][kq * 4 + 3] = bf2f(v.w);
    }
    __syncthreads();
#pragma unroll 4
    for (int k = 0; k < FHID; ++k) {
        float a = hs[lane][k];
        const float* wrow = W2 + k * FOUT + cg * 8;
#pragma unroll
        for (int c = 0; c < 8; ++c) acc[c] += a * wrow[c];
    }
    if (row < NN) {
        uint4 st;
        st.x = (unsigned)f2bf(acc[0]) | ((unsigned)f2bf(acc[1]) << 16);
        st.y = (unsigned)f2bf(acc[2]) | ((unsigned)f2bf(acc[3]) << 16);
        st.z = (unsigned)f2bf(acc[4]) | ((unsigned)f2bf(acc[5]) << 16);
        st.w = (unsigned)f2bf(acc[6]) | ((unsigned)f2bf(acc[7]) << 16);
        *(uint4*)(out + (size_t)row * FOUT + cg * 8) = st;
    }
}

// ------- SpMM2 + bias + log_softmax (fp32 out) -------
// 8-lane group per row (8 x uint2 = 64B), 8 rows/wave, 32 rows/block.
__global__ __launch_bounds__(256) void spmm2_kernel(const int* __restrict__ rowptr,
                                                    const int2* __restrict__ epack,
                                                    const unsigned short* __restrict__ dense,
                                                    const float* __restrict__ b2,
                                                    float* __restrict__ out) {
    const int gtid = blockIdx.x * 256 + threadIdx.x;
    const int wid = gtid >> 6;
    const int lane = threadIdx.x & 63;
    const int o = lane >> 3;  // 0..7
    const int sl = lane & 7;  // 0..7
    const int row = wid * 8 + o;  // grid exact: NN/32 blocks
    const int start = rowptr[row];
    const int cnt = rowptr[row + 1] - start;
    float acc[4];
#pragma unroll
    for (int i = 0; i < 4; ++i) acc[i] = 0.f;

    for (int base = 0; base < cnt; base += 8) {
        const int rem = cnt - base;
        int2 p = make_int2(0, 0);
        if (sl < rem) p = epack[start + base + sl];
        const int jn = min(8, rem);
        for (int j = 0; j < jn; j += 4) {
            int cj[4];
            float vj[4];
            uint2 d[4];
#pragma unroll
            for (int k = 0; k < 4; ++k) {
                cj[k] = __shfl(p.x, o * 8 + j + k, 64);
                vj[k] = __shfl(__int_as_float(p.y), o * 8 + j + k, 64);
            }
#pragma unroll
            for (int k = 0; k < 4; ++k)
                d[k] = *(const uint2*)(dense + (size_t)cj[k] * FOUT + sl * 4);
#pragma unroll
            for (int k = 0; k < 4; ++k) {
                acc[0] += vj[k] * bflo(d[k].x);
                acc[1] += vj[k] * bfhi(d[k].x);
                acc[2] += vj[k] * bflo(d[k].y);
                acc[3] += vj[k] * bfhi(d[k].y);
            }
        }
    }
    float4 bb = *(const float4*)(b2 + sl * 4);
    acc[0] += bb.x;
    acc[1] += bb.y;
    acc[2] += bb.z;
    acc[3] += bb.w;
    float m = fmaxf(fmaxf(acc[0], acc[1]), fmaxf(acc[2], acc[3]));
#pragma unroll
    for (int mask = 4; mask >= 1; mask >>= 1) m = fmaxf(m, __shfl_xor(m, mask, 64));
    float ssum = expf(acc[0] - m) + expf(acc[1] - m) + expf(acc[2] - m) + expf(acc[3] - m);
#pragma unroll
    for (int mask = 4; mask >= 1; mask >>= 1) ssum += __shfl_xor(ssum, mask, 64);
    float lse = m + logf(ssum);
    float4 st = make_float4(acc[0] - lse, acc[1] - lse, acc[2] - lse, acc[3] - lse);
    *(float4*)(out + (size_t)row * FOUT + sl * 4) = st;
}

extern "C" void kernel_launch(void* const* d_in, const int* in_sizes, int n_in,
                              void* d_out, int out_size, void* d_ws, size_t ws_size,
                              hipStream_t stream) {
    const float* x = (const float*)d_in[0];
    const int* erow = (const int*)d_in[1];
    const int* ecol = (const int*)d_in[2];
    const float* eval = (const float*)d_in[3];
    const float* W1 = (const float*)d_in[4];
    const float* b1 = (const float*)d_in[5];
    const float* W2 = (const float*)d_in[6];
    const float* b2 = (const float*)d_in[7];
    float* out = (float*)d_out;

    char* ws = (char*)d_ws;
    size_t off_b = 0;
    auto walloc = [&](size_t bytes) -> void* {
        void* p = ws + off_b;
        off_b = (off_b + bytes + 255) & ~(size_t)255;
        return p;
    };
    int2* epack = (int2*)walloc((size_t)NE * 8);  // persists through spmm2
    int* rowptr = (int*)walloc((size_t)(NN + 1) * 4);
    int* cntG = (int*)walloc((size_t)TOT * 4);
    int* off = (int*)walloc((size_t)TOT * 4);
    int* bstart = (int*)walloc((size_t)(NBUCK + 1) * 4);
    int* partials = (int*)walloc(4096);
    unsigned short* W1t = (unsigned short*)walloc((size_t)FHID * FIN * 2);
    // union: bcolval (CSR build) / support1+h (dense phase). Stream-ordered.
    char* uni = (char*)walloc((size_t)NN * FHID * 2 * 2);
    int2* bcolval = (int2*)uni;
    unsigned short* support1 = (unsigned short*)uni;
    unsigned short* h = (unsigned short*)(uni + (size_t)NN * FHID * 2);
    unsigned short* support2 = support1;  // support1 dead after spmm1

    prep_w1<<<256, 256, 0, stream>>>(W1, W1t);
    hist_part<<<NPART, 256, 0, stream>>>(erow, cntG);
    scan1_kernel<<<NSCAN1, 256, 0, stream>>>(cntG, off, partials);
    scan2_kernel<<<1, 128, 0, stream>>>(partials);
    scan3_kernel<<<NSCAN1, 256, 0, stream>>>(off, partials);
    make_bstart<<<2, 256, 0, stream>>>(off, bstart);
    scatter_part<<<NPART, 256, 0, stream>>>(erow, ecol, eval, off, bcolval);
    bucket_to_csr<<<NBUCK, 256, 0, stream>>>(bstart, bcolval, rowptr, epack);

    gemm1_mfma<<<(NN + 127) / 128, 256, 0, stream>>>(x, W1t, support1);
    spmm1_kernel<<<NN / 16, 256, 0, stream>>>(rowptr, epack, support1, b1, h);
    gemm2_kernel<<<(NN + 63) / 64, 256, 0, stream>>>(h, W2, support2);
    spmm2_kernel<<<NN / 32, 256, 0, stream>>>(rowptr, epack, support2, b2, out);
}